// Round 10
// baseline (77.121 us; speedup 1.0000x reference)
//
#include <hip/hip_runtime.h>
#include <math.h>

// Fully-analytic spectral solution of the ring RNN — SINGLE KERNEL.
//   r_record[s] = M^s (h/tau),  M = (1-c)I + cW,  c = dt/tau = 0.05
// W circulant von-Mises: lambda_k = 0.95 + 0.045 I_k(b)/I_0(b), b = 16/pi^2
// (compile-time). h's grid projections closed-form; KM=4.
//   r_s[i,b] = 50 e^{-b} I_0 lam_0^s
//            + sum_k lam_k^s 100 e^{-b} I_k [cos(k th_b) cos(k phi_i)
//                                          + sin(k th_b) sin(k phi_i)]
// R10 delta vs R9: main-loop stores are NONTEMPORAL (no L2 allocate) —
// isolating the L2 write-allocate-pressure hypothesis on the proven
// aligned-quad stream. Everything else identical to R9 (43.6 us).

#define NN      4096
#define NB      256
#define NSTEPS  61
#define KM      4

#define PHI_STEP 0.0015339807878856412f   // 2*pi/4096

// cos/sin of m*PHI_STEP (compile-time)
#define C1D 0.99999882345148f
#define S1D 0.00153398018629f
#define C2D 0.99999529380590f
#define S2D 0.00306795676300f
#define C3D 0.99998941106350f
#define S3D 0.00460192612050f
#define C4D 0.99998117522360f
#define S4D 0.00613588464910f
#define C6D 0.99995764455250f
#define S6D 0.00920375478170f

// e^{-b} I_k(b) at b = 16/pi^2 = 1.6211389382774045
#define EB_I0 0.35050527f
#define EB_I1 0.21895491f
#define EB_I2 0.08038041f
#define EB_I3 0.02062404f
#define EB_I4 0.00404908f
// lambda_k = 0.95 + 0.045 I_k/I_0 ; L2_k = log2(lambda_k)
#define L2_0 (-0.0072316f)
#define L2_1 (-0.0319307f)
#define L2_2 (-0.0584121f)
#define L2_3 (-0.0699827f)
#define L2_4 (-0.0732113f)

#define NROWS   (NSTEPS * NN)         // 249856 global rows
#define NTRAIL  (NROWS / 64)          // 3904 trailing boundary quads

typedef float fx4 __attribute__((ext_vector_type(4)));

__device__ __forceinline__ float phiF(int i) { return PHI_STEP * (float)i; }
__device__ __forceinline__ float p2(float x) { return __builtin_amdgcn_exp2f(x); }

__global__ void __launch_bounds__(256)
rnn_ring_all(const float* __restrict__ theta, float* __restrict__ out) {
    int blk = blockIdx.x;
    int tid = threadIdx.x;
    __shared__ float lds[8][NB];      // rows 0..3: Qc_k ; rows 4..7: Qs_k

    if (blk < NSTEPS * 16) {
        int s    = blk >> 4;
        int i0   = (blk & 15) << 8;
        int lane = tid & 63;
        int w    = tid >> 6;
        float sf = (float)s;

        // ---- phase 1: per-batch coefficients (one sincos per thread) ----
        {
            float g1 = 100.0f * EB_I1 * p2(sf * L2_1);
            float g2 = 100.0f * EB_I2 * p2(sf * L2_2);
            float g3 = 100.0f * EB_I3 * p2(sf * L2_3);
            float g4 = 100.0f * EB_I4 * p2(sf * L2_4);
            float th = theta[tid];
            float ct, st;
            __sincosf(th, &st, &ct);
            float t2 = 2.0f * ct;
            float c2t = t2 * ct - 1.0f, s2t = t2 * st;
            float c3t = t2 * c2t - ct,  s3t = t2 * s2t - st;
            float c4t = t2 * c3t - c2t, s4t = t2 * s3t - s2t;
            int p = (tid - 3) & 255;          // SUV shift: quad l = b 4l+3..4l+6
            lds[0][p] = g1 * ct;  lds[4][p] = g1 * st;
            lds[1][p] = g2 * c2t; lds[5][p] = g2 * s2t;
            lds[2][p] = g3 * c3t; lds[6][p] = g3 * s3t;
            lds[3][p] = g4 * c4t; lds[7][p] = g4 * s4t;
        }
        __syncthreads();

        float P0S = 50.0f * EB_I0 * p2(sf * L2_0);   // b-independent mode 0

        fx4 Q1c = *reinterpret_cast<const fx4*>(&lds[0][4 * lane]);
        fx4 Q2c = *reinterpret_cast<const fx4*>(&lds[1][4 * lane]);
        fx4 Qc3 = *reinterpret_cast<const fx4*>(&lds[2][4 * lane]);
        fx4 Qc4 = *reinterpret_cast<const fx4*>(&lds[3][4 * lane]);
        fx4 Q1s = *reinterpret_cast<const fx4*>(&lds[4][4 * lane]);
        fx4 Q2s = *reinterpret_cast<const fx4*>(&lds[5][4 * lane]);
        fx4 Qs3 = *reinterpret_cast<const fx4*>(&lds[6][4 * lane]);
        fx4 Qs4 = *reinterpret_cast<const fx4*>(&lds[7][4 * lane]);

        // rotated coefficient sets for k=1,2 at row offsets d=0..3
        fx4 Pc1[4], Ps1[4], Pc2[4], Ps2[4];
        Pc1[0] = Q1c;                     Ps1[0] = Q1s;
        Pc2[0] = Q2c;                     Ps2[0] = Q2s;
        Pc1[1] = C1D * Q1c + S1D * Q1s;   Ps1[1] = C1D * Q1s - S1D * Q1c;
        Pc1[2] = C2D * Q1c + S2D * Q1s;   Ps1[2] = C2D * Q1s - S2D * Q1c;
        Pc1[3] = C3D * Q1c + S3D * Q1s;   Ps1[3] = C3D * Q1s - S3D * Q1c;
        Pc2[1] = C2D * Q2c + S2D * Q2s;   Ps2[1] = C2D * Q2s - S2D * Q2c;
        Pc2[2] = C4D * Q2c + S4D * Q2s;   Ps2[2] = C4D * Q2s - S4D * Q2c;
        Pc2[3] = C6D * Q2c + S6D * Q2s;   Ps2[3] = C6D * Q2s - S6D * Q2c;

        int row0 = i0 + 64 * w;
        float ph = phiF(row0);
        float c1 = cosf(ph), s1 = sinf(ph);
        float t2 = 2.0f * c1;
        float c2 = t2 * c1 - 1.0f, s2 = t2 * s1;
        float c3 = t2 * c2 - c1,   s3 = t2 * s2 - s1;
        float c4 = t2 * c3 - c2,   s4 = t2 * s3 - s2;

        float* rowptr = out + NSTEPS + ((size_t)s * NN + row0) * NB;
        float pax = 0.0f;
        bool b63 = (lane == 63);

        for (int g = 0; g < 16; ++g) {
            fx4 ahi = P0S + c3 * Qc3 + s3 * Qs3 + c4 * Qc4 + s4 * Qs4;
#pragma unroll
            for (int d = 0; d < 4; ++d) {
                fx4 a = ahi + c1 * Pc1[d] + s1 * Ps1[d]
                            + c2 * Pc2[d] + s2 * Ps2[d];
                if (b63) {
                    if ((g | d) != 0) {
                        fx4 q; q.x = pax; q.y = a.y; q.z = a.z; q.w = a.w;
                        __builtin_nontemporal_store(
                            q, reinterpret_cast<fx4*>(rowptr - 1));
                    }
                    pax = a.x;
                } else {
                    __builtin_nontemporal_store(
                        a, reinterpret_cast<fx4*>(rowptr + 3 + 4 * lane));
                }
                rowptr += NB;
            }
            float c1n = c1 * C4D - s1 * S4D;   // advance base angle 4 steps
            float s1n = s1 * C4D + c1 * S4D;
            c1 = c1n; s1 = s1n;
            t2 = 2.0f * c1;
            c2 = t2 * c1 - 1.0f; s2 = t2 * s1;
            c3 = t2 * c2 - c1;   s3 = t2 * s2 - s1;
            c4 = t2 * c3 - c2;   s4 = t2 * s3 - s2;
        }
    } else {
        // ---- tail: trailing quads (rg%64==63), head, t_record ----
        int g = (blk - NSTEPS * 16) * 256 + tid;     // 0 .. 4095
        if (g < NTRAIL) {
            int rg  = 64 * g + 63;
            int s   = rg >> 12;
            int row = rg & (NN - 1);
            // x = r(s,row,255)
            float th255 = theta[255];
            float ct, st; __sincosf(th255, &st, &ct);
            float t2b = 2.0f * ct;
            float c2t = t2b * ct - 1.0f, s2t = t2b * st;
            float c3t = t2b * c2t - ct,  s3t = t2b * s2t - st;
            float c4t = t2b * c3t - c2t, s4t = t2b * s3t - s2t;
            float ph = phiF(row);
            float c = cosf(ph), sv = sinf(ph);
            float t2 = 2.0f * c;
            float C2 = t2 * c - 1.0f, S2 = t2 * sv;
            float C3 = t2 * C2 - c,   S3 = t2 * S2 - sv;
            float C4 = t2 * C3 - C2,  S4 = t2 * S3 - S2;
            float sf = (float)s;
            float x = 50.0f * EB_I0 * p2(sf * L2_0)
                + 100.0f * EB_I1 * p2(sf * L2_1) * (c  * ct  + sv * st)
                + 100.0f * EB_I2 * p2(sf * L2_2) * (C2 * c2t + S2 * s2t)
                + 100.0f * EB_I3 * p2(sf * L2_3) * (C3 * c3t + S3 * s3t)
                + 100.0f * EB_I4 * p2(sf * L2_4) * (C4 * c4t + S4 * s4t);
            float* dst = out + NSTEPS + (size_t)rg * NB + 255;
            if (rg == NROWS - 1) {
                *dst = x;                              // global tail
            } else {
                int rg2  = rg + 1;
                int s2i  = rg2 >> 12;
                int row2 = rg2 & (NN - 1);
                float ph2 = phiF(row2);
                float cc = cosf(ph2), ss = sinf(ph2);
                float u2 = 2.0f * cc;
                float D2 = u2 * cc - 1.0f, E2 = u2 * ss;
                float D3 = u2 * D2 - cc,   E3 = u2 * E2 - ss;
                float D4 = u2 * D3 - D2,   E4 = u2 * E3 - E2;
                float sf2 = (float)s2i;
                float l0 = 50.0f  * EB_I0 * p2(sf2 * L2_0);
                float l1 = 100.0f * EB_I1 * p2(sf2 * L2_1);
                float l2 = 100.0f * EB_I2 * p2(sf2 * L2_2);
                float l3 = 100.0f * EB_I3 * p2(sf2 * L2_3);
                float l4 = 100.0f * EB_I4 * p2(sf2 * L2_4);
                float yzw[3];
#pragma unroll
                for (int b = 0; b < 3; ++b) {
                    float thb = theta[b];
                    float cb, sb; __sincosf(thb, &sb, &cb);
                    float v2 = 2.0f * cb;
                    float cb2 = v2 * cb - 1.0f, sb2 = v2 * sb;
                    float cb3 = v2 * cb2 - cb,  sb3 = v2 * sb2 - sb;
                    float cb4 = v2 * cb3 - cb2, sb4 = v2 * sb3 - sb2;
                    yzw[b] = l0
                        + l1 * (cc * cb  + ss * sb)
                        + l2 * (D2 * cb2 + E2 * sb2)
                        + l3 * (D3 * cb3 + E3 * sb3)
                        + l4 * (D4 * cb4 + E4 * sb4);
                }
                fx4 q; q.x = x; q.y = yzw[0]; q.z = yzw[1]; q.w = yzw[2];
                *reinterpret_cast<fx4*>(dst) = q;
            }
        } else if (g < NTRAIL + 61) {
            out[g - NTRAIL] = 0.001f * (float)(g - NTRAIL);   // t_record
        } else if (g < NTRAIL + 64) {
            int b = g - (NTRAIL + 61);       // head: r(0, row0, b), b=0,1,2
            float thb = theta[b];
            float cb, sb; __sincosf(thb, &sb, &cb);
            float v2 = 2.0f * cb;
            float cb2 = v2 * cb - 1.0f, sb2 = v2 * sb;
            float cb3 = v2 * cb2 - cb,  sb3 = v2 * sb2 - sb;
            float cb4 = v2 * cb3 - cb2;
            out[NSTEPS + b] = 50.0f * EB_I0 + 100.0f * (EB_I1 * cb
                + EB_I2 * cb2 + EB_I3 * cb3 + EB_I4 * cb4);
        }
    }
}

extern "C" void kernel_launch(void* const* d_in, const int* in_sizes, int n_in,
                              void* d_out, int out_size, void* d_ws, size_t ws_size,
                              hipStream_t stream) {
    (void)in_sizes; (void)n_in; (void)out_size; (void)d_ws; (void)ws_size;
    const float* theta = (const float*)d_in[0];
    float* out = (float*)d_out;
    rnn_ring_all<<<dim3(NSTEPS * 16 + 16), dim3(256), 0, stream>>>(theta, out);
}

// Round 11
// 43.272 us; speedup vs baseline: 1.7822x; 1.7822x over previous
//
#include <hip/hip_runtime.h>
#include <math.h>

// Fully-analytic spectral solution of the ring RNN — SINGLE KERNEL.
//   r_record[s] = M^s (h/tau),  M = (1-c)I + cW,  c = dt/tau = 0.05
// W circulant von-Mises: lambda_k = 0.95 + 0.045 I_k(b)/I_0(b), b = 16/pi^2
// (compile-time). h's grid projections closed-form; KM=4.
//   r_s[i,b] = 50 e^{-b} I_0 lam_0^s
//            + sum_k lam_k^s 100 e^{-b} I_k [cos(k th_b) cos(k phi_i)
//                                          + sin(k th_b) sin(k phi_i)]
//
// R11 = exact revert to R9 (43.6 us). R10's A/B proved NT (no-L2-allocate)
// stores run at ~3.3 TB/s vs ~5.9 TB/s through L2 on this write stream —
// MI355X streaming fp32 stores MUST go through L2. Regular stores restored.

#define NN      4096
#define NB      256
#define NSTEPS  61
#define KM      4

#define PHI_STEP 0.0015339807878856412f   // 2*pi/4096

// cos/sin of m*PHI_STEP (compile-time)
#define C1D 0.99999882345148f
#define S1D 0.00153398018629f
#define C2D 0.99999529380590f
#define S2D 0.00306795676300f
#define C3D 0.99998941106350f
#define S3D 0.00460192612050f
#define C4D 0.99998117522360f
#define S4D 0.00613588464910f
#define C6D 0.99995764455250f
#define S6D 0.00920375478170f

// e^{-b} I_k(b) at b = 16/pi^2 = 1.6211389382774045
#define EB_I0 0.35050527f
#define EB_I1 0.21895491f
#define EB_I2 0.08038041f
#define EB_I3 0.02062404f
#define EB_I4 0.00404908f
// lambda_k = 0.95 + 0.045 I_k/I_0 ; L2_k = log2(lambda_k)
#define L2_0 (-0.0072316f)
#define L2_1 (-0.0319307f)
#define L2_2 (-0.0584121f)
#define L2_3 (-0.0699827f)
#define L2_4 (-0.0732113f)

#define NROWS   (NSTEPS * NN)         // 249856 global rows
#define NTRAIL  (NROWS / 64)          // 3904 trailing boundary quads

typedef float fx4 __attribute__((ext_vector_type(4)));

__device__ __forceinline__ float phiF(int i) { return PHI_STEP * (float)i; }
__device__ __forceinline__ float p2(float x) { return __builtin_amdgcn_exp2f(x); }

__global__ void __launch_bounds__(256)
rnn_ring_all(const float* __restrict__ theta, float* __restrict__ out) {
    int blk = blockIdx.x;
    int tid = threadIdx.x;
    __shared__ float lds[8][NB];      // rows 0..3: Qc_k ; rows 4..7: Qs_k

    if (blk < NSTEPS * 16) {
        int s    = blk >> 4;
        int i0   = (blk & 15) << 8;
        int lane = tid & 63;
        int w    = tid >> 6;
        float sf = (float)s;

        // ---- phase 1: per-batch coefficients (one sincos per thread) ----
        {
            float g1 = 100.0f * EB_I1 * p2(sf * L2_1);
            float g2 = 100.0f * EB_I2 * p2(sf * L2_2);
            float g3 = 100.0f * EB_I3 * p2(sf * L2_3);
            float g4 = 100.0f * EB_I4 * p2(sf * L2_4);
            float th = theta[tid];
            float ct, st;
            __sincosf(th, &st, &ct);
            float t2 = 2.0f * ct;
            float c2t = t2 * ct - 1.0f, s2t = t2 * st;
            float c3t = t2 * c2t - ct,  s3t = t2 * s2t - st;
            float c4t = t2 * c3t - c2t, s4t = t2 * s3t - s2t;
            int p = (tid - 3) & 255;          // SUV shift: quad l = b 4l+3..4l+6
            lds[0][p] = g1 * ct;  lds[4][p] = g1 * st;
            lds[1][p] = g2 * c2t; lds[5][p] = g2 * s2t;
            lds[2][p] = g3 * c3t; lds[6][p] = g3 * s3t;
            lds[3][p] = g4 * c4t; lds[7][p] = g4 * s4t;
        }
        __syncthreads();

        float P0S = 50.0f * EB_I0 * p2(sf * L2_0);   // b-independent mode 0

        fx4 Q1c = *reinterpret_cast<const fx4*>(&lds[0][4 * lane]);
        fx4 Q2c = *reinterpret_cast<const fx4*>(&lds[1][4 * lane]);
        fx4 Qc3 = *reinterpret_cast<const fx4*>(&lds[2][4 * lane]);
        fx4 Qc4 = *reinterpret_cast<const fx4*>(&lds[3][4 * lane]);
        fx4 Q1s = *reinterpret_cast<const fx4*>(&lds[4][4 * lane]);
        fx4 Q2s = *reinterpret_cast<const fx4*>(&lds[5][4 * lane]);
        fx4 Qs3 = *reinterpret_cast<const fx4*>(&lds[6][4 * lane]);
        fx4 Qs4 = *reinterpret_cast<const fx4*>(&lds[7][4 * lane]);

        // rotated coefficient sets for k=1,2 at row offsets d=0..3
        fx4 Pc1[4], Ps1[4], Pc2[4], Ps2[4];
        Pc1[0] = Q1c;                     Ps1[0] = Q1s;
        Pc2[0] = Q2c;                     Ps2[0] = Q2s;
        Pc1[1] = C1D * Q1c + S1D * Q1s;   Ps1[1] = C1D * Q1s - S1D * Q1c;
        Pc1[2] = C2D * Q1c + S2D * Q1s;   Ps1[2] = C2D * Q1s - S2D * Q1c;
        Pc1[3] = C3D * Q1c + S3D * Q1s;   Ps1[3] = C3D * Q1s - S3D * Q1c;
        Pc2[1] = C2D * Q2c + S2D * Q2s;   Ps2[1] = C2D * Q2s - S2D * Q2c;
        Pc2[2] = C4D * Q2c + S4D * Q2s;   Ps2[2] = C4D * Q2s - S4D * Q2c;
        Pc2[3] = C6D * Q2c + S6D * Q2s;   Ps2[3] = C6D * Q2s - S6D * Q2c;

        int row0 = i0 + 64 * w;
        float ph = phiF(row0);
        float c1 = cosf(ph), s1 = sinf(ph);
        float t2 = 2.0f * c1;
        float c2 = t2 * c1 - 1.0f, s2 = t2 * s1;
        float c3 = t2 * c2 - c1,   s3 = t2 * s2 - s1;
        float c4 = t2 * c3 - c2,   s4 = t2 * s3 - s2;

        float* rowptr = out + NSTEPS + ((size_t)s * NN + row0) * NB;
        float pax = 0.0f;
        bool b63 = (lane == 63);

        for (int g = 0; g < 16; ++g) {
            fx4 ahi = P0S + c3 * Qc3 + s3 * Qs3 + c4 * Qc4 + s4 * Qs4;
#pragma unroll
            for (int d = 0; d < 4; ++d) {
                fx4 a = ahi + c1 * Pc1[d] + s1 * Ps1[d]
                            + c2 * Pc2[d] + s2 * Ps2[d];
                if (b63) {
                    if ((g | d) != 0) {
                        fx4 q; q.x = pax; q.y = a.y; q.z = a.z; q.w = a.w;
                        *reinterpret_cast<fx4*>(rowptr - 1) = q;
                    }
                    pax = a.x;
                } else {
                    *reinterpret_cast<fx4*>(rowptr + 3 + 4 * lane) = a;
                }
                rowptr += NB;
            }
            float c1n = c1 * C4D - s1 * S4D;   // advance base angle 4 steps
            float s1n = s1 * C4D + c1 * S4D;
            c1 = c1n; s1 = s1n;
            t2 = 2.0f * c1;
            c2 = t2 * c1 - 1.0f; s2 = t2 * s1;
            c3 = t2 * c2 - c1;   s3 = t2 * s2 - s1;
            c4 = t2 * c3 - c2;   s4 = t2 * s3 - s2;
        }
    } else {
        // ---- tail: trailing quads (rg%64==63), head, t_record ----
        int g = (blk - NSTEPS * 16) * 256 + tid;     // 0 .. 4095
        if (g < NTRAIL) {
            int rg  = 64 * g + 63;
            int s   = rg >> 12;
            int row = rg & (NN - 1);
            // x = r(s,row,255)
            float th255 = theta[255];
            float ct, st; __sincosf(th255, &st, &ct);
            float t2b = 2.0f * ct;
            float c2t = t2b * ct - 1.0f, s2t = t2b * st;
            float c3t = t2b * c2t - ct,  s3t = t2b * s2t - st;
            float c4t = t2b * c3t - c2t, s4t = t2b * s3t - s2t;
            float ph = phiF(row);
            float c = cosf(ph), sv = sinf(ph);
            float t2 = 2.0f * c;
            float C2 = t2 * c - 1.0f, S2 = t2 * sv;
            float C3 = t2 * C2 - c,   S3 = t2 * S2 - sv;
            float C4 = t2 * C3 - C2,  S4 = t2 * S3 - S2;
            float sf = (float)s;
            float x = 50.0f * EB_I0 * p2(sf * L2_0)
                + 100.0f * EB_I1 * p2(sf * L2_1) * (c  * ct  + sv * st)
                + 100.0f * EB_I2 * p2(sf * L2_2) * (C2 * c2t + S2 * s2t)
                + 100.0f * EB_I3 * p2(sf * L2_3) * (C3 * c3t + S3 * s3t)
                + 100.0f * EB_I4 * p2(sf * L2_4) * (C4 * c4t + S4 * s4t);
            float* dst = out + NSTEPS + (size_t)rg * NB + 255;
            if (rg == NROWS - 1) {
                *dst = x;                              // global tail
            } else {
                int rg2  = rg + 1;
                int s2i  = rg2 >> 12;
                int row2 = rg2 & (NN - 1);
                float ph2 = phiF(row2);
                float cc = cosf(ph2), ss = sinf(ph2);
                float u2 = 2.0f * cc;
                float D2 = u2 * cc - 1.0f, E2 = u2 * ss;
                float D3 = u2 * D2 - cc,   E3 = u2 * E2 - ss;
                float D4 = u2 * D3 - D2,   E4 = u2 * E3 - E2;
                float sf2 = (float)s2i;
                float l0 = 50.0f  * EB_I0 * p2(sf2 * L2_0);
                float l1 = 100.0f * EB_I1 * p2(sf2 * L2_1);
                float l2 = 100.0f * EB_I2 * p2(sf2 * L2_2);
                float l3 = 100.0f * EB_I3 * p2(sf2 * L2_3);
                float l4 = 100.0f * EB_I4 * p2(sf2 * L2_4);
                float yzw[3];
#pragma unroll
                for (int b = 0; b < 3; ++b) {
                    float thb = theta[b];
                    float cb, sb; __sincosf(thb, &sb, &cb);
                    float v2 = 2.0f * cb;
                    float cb2 = v2 * cb - 1.0f, sb2 = v2 * sb;
                    float cb3 = v2 * cb2 - cb,  sb3 = v2 * sb2 - sb;
                    float cb4 = v2 * cb3 - cb2, sb4 = v2 * sb3 - sb2;
                    yzw[b] = l0
                        + l1 * (cc * cb  + ss * sb)
                        + l2 * (D2 * cb2 + E2 * sb2)
                        + l3 * (D3 * cb3 + E3 * sb3)
                        + l4 * (D4 * cb4 + E4 * sb4);
                }
                fx4 q; q.x = x; q.y = yzw[0]; q.z = yzw[1]; q.w = yzw[2];
                *reinterpret_cast<fx4*>(dst) = q;
            }
        } else if (g < NTRAIL + 61) {
            out[g - NTRAIL] = 0.001f * (float)(g - NTRAIL);   // t_record
        } else if (g < NTRAIL + 64) {
            int b = g - (NTRAIL + 61);       // head: r(0, row0, b), b=0,1,2
            float thb = theta[b];
            float cb, sb; __sincosf(thb, &sb, &cb);
            float v2 = 2.0f * cb;
            float cb2 = v2 * cb - 1.0f, sb2 = v2 * sb;
            float cb3 = v2 * cb2 - cb,  sb3 = v2 * sb2 - sb;
            float cb4 = v2 * cb3 - cb2;
            out[NSTEPS + b] = 50.0f * EB_I0 + 100.0f * (EB_I1 * cb
                + EB_I2 * cb2 + EB_I3 * cb3 + EB_I4 * cb4);
        }
    }
}

extern "C" void kernel_launch(void* const* d_in, const int* in_sizes, int n_in,
                              void* d_out, int out_size, void* d_ws, size_t ws_size,
                              hipStream_t stream) {
    (void)in_sizes; (void)n_in; (void)out_size; (void)d_ws; (void)ws_size;
    const float* theta = (const float*)d_in[0];
    float* out = (float*)d_out;
    rnn_ring_all<<<dim3(NSTEPS * 16 + 16), dim3(256), 0, stream>>>(theta, out);
}